// Round 9
// baseline (364.283 us; speedup 1.0000x reference)
//
#include <hip/hip_runtime.h>

#define HDIM 96

__global__ void zero_k(int* __restrict__ p, int n) {
  int i = blockIdx.x * blockDim.x + threadIdx.x;
  if (i < n) p[i] = 0;
}

// count in-degree AND record each edge's arrival rank at its dst
__global__ void deg_rank_k(const int* __restrict__ dst, int* __restrict__ indeg,
                           int* __restrict__ rank, int e) {
  int i = blockIdx.x * blockDim.x + threadIdx.x;
  if (i < e) rank[i] = atomicAdd(&indeg[dst[i]], 1);
}

__device__ __forceinline__ int wave_incl_scan(int v, int lane) {
#pragma unroll
  for (int off = 1; off < 64; off <<= 1) {
    int t = __shfl_up(v, off, 64);
    if (lane >= off) v += t;
  }
  return v;
}

// Phase A: bsum[b] = sum of indeg[b*1024 .. b*1024+1024)
__global__ __launch_bounds__(1024) void scan_a_k(const int* __restrict__ indeg,
                                                 int* __restrict__ bsum, int n) {
  const int tid = threadIdx.x;
  const int i = blockIdx.x * 1024 + tid;
  int v = (i < n) ? indeg[i] : 0;
#pragma unroll
  for (int off = 32; off; off >>= 1) v += __shfl_down(v, off, 64);
  __shared__ int ws[16];
  if ((tid & 63) == 0) ws[tid >> 6] = v;
  __syncthreads();
  if (tid < 16) {
    int s = ws[tid];
#pragma unroll
    for (int off = 8; off; off >>= 1) s += __shfl_down(s, off, 16);
    if (tid == 0) bsum[blockIdx.x] = s;
  }
}

// Phase B: exclusive scan of bsum[0..nb) -> bbase; offsets[n] = grand total. nb <= 1024.
__global__ __launch_bounds__(1024) void scan_b_k(const int* __restrict__ bsum,
                                                 int* __restrict__ bbase,
                                                 int* __restrict__ offsets, int nb, int n) {
  __shared__ int ws[16];
  const int tid = threadIdx.x, lane = tid & 63, w = tid >> 6;
  const int v = (tid < nb) ? bsum[tid] : 0;
  int incl = wave_incl_scan(v, lane);
  if (lane == 63) ws[w] = incl;
  __syncthreads();
  if (tid < 16) {
    int s = ws[tid];
#pragma unroll
    for (int off = 1; off < 16; off <<= 1) {
      int t = __shfl_up(s, off, 16);
      if (tid >= off) s += t;
    }
    ws[tid] = s;
  }
  __syncthreads();
  incl += (w > 0 ? ws[w - 1] : 0);
  if (tid < nb) bbase[tid] = incl - v;
  if (tid == 0) offsets[n] = ws[15];
}

// Phase C: per-chunk rescan + base add; also dis = rsqrt(1+indeg)
__global__ __launch_bounds__(1024) void scan_c_k(const int* __restrict__ indeg,
                                                 const int* __restrict__ bbase,
                                                 int* __restrict__ offsets,
                                                 float* __restrict__ dis, int n) {
  __shared__ int ws[16];
  const int tid = threadIdx.x, lane = tid & 63, w = tid >> 6;
  const int i = blockIdx.x * 1024 + tid;
  const int v = (i < n) ? indeg[i] : 0;
  int incl = wave_incl_scan(v, lane);
  if (lane == 63) ws[w] = incl;
  __syncthreads();
  if (tid < 16) {
    int s = ws[tid];
#pragma unroll
    for (int off = 1; off < 16; off <<= 1) {
      int t = __shfl_up(s, off, 16);
      if (tid >= off) s += t;
    }
    ws[tid] = s;
  }
  __syncthreads();
  incl += (w > 0 ? ws[w - 1] : 0);
  if (i < n) {
    offsets[i] = bbase[blockIdx.x] + incl - v;
    dis[i] = rsqrtf((float)(1 + v));
  }
}

// atomic-free slot calc; fire-and-forget atomicExch avoids partial-line store amplification
__global__ void place_k(const int* __restrict__ src, const int* __restrict__ dst,
                        const int* __restrict__ rank, const int* __restrict__ offsets,
                        int* __restrict__ csr_src, int e) {
  int i = blockIdx.x * blockDim.x + threadIdx.x;
  if (i >= e) return;
  int d = dst[i];
  atomicExch(&csr_src[offsets[d] + rank[i]], src[i]);
}

// o[i,:] = dis[i] * x[i,:]
__global__ void scale_k(const float* __restrict__ x, const float* __restrict__ dis,
                        float* __restrict__ o, int n) {
  int t = blockIdx.x * blockDim.x + threadIdx.x;
  if (t >= n * 24) return;
  const float d = dis[t / 24];
  float4 v = ((const float4*)x)[t];
  v.x *= d; v.y *= d; v.z *= d; v.w *= d;
  ((float4*)o)[t] = v;
}

// agg[d,:] = dis[d] * ( hp[d,:] + sum_{s->d} hp[s,:] )   (hp is pre-scaled dis*h)
__global__ __launch_bounds__(192) void gather_k(
    const int* __restrict__ csr_src, const int* __restrict__ offsets,
    const float* __restrict__ dis, const float* __restrict__ hp,
    float* __restrict__ agg, int n) {
  const int tid  = threadIdx.x;
  const int node = blockIdx.x * 8 + tid / 24;
  const int q    = tid % 24;
  if (node >= n) return;
  float4 acc = ((const float4*)(hp + (size_t)node * HDIM))[q];   // self term
  int i = offsets[node];
  const int end = offsets[node + 1];
  for (; i + 3 < end; i += 4) {
    const int s0 = csr_src[i], s1 = csr_src[i + 1], s2 = csr_src[i + 2], s3 = csr_src[i + 3];
    const float4 v0 = ((const float4*)(hp + (size_t)s0 * HDIM))[q];
    const float4 v1 = ((const float4*)(hp + (size_t)s1 * HDIM))[q];
    const float4 v2 = ((const float4*)(hp + (size_t)s2 * HDIM))[q];
    const float4 v3 = ((const float4*)(hp + (size_t)s3 * HDIM))[q];
    acc.x += v0.x + v1.x + v2.x + v3.x;
    acc.y += v0.y + v1.y + v2.y + v3.y;
    acc.z += v0.z + v1.z + v2.z + v3.z;
    acc.w += v0.w + v1.w + v2.w + v3.w;
  }
  for (; i < end; i++) {
    const int s0 = csr_src[i];
    const float4 v0 = ((const float4*)(hp + (size_t)s0 * HDIM))[q];
    acc.x += v0.x; acc.y += v0.y; acc.z += v0.z; acc.w += v0.w;
  }
  const float dd = dis[node];
  acc.x *= dd; acc.y *= dd; acc.z *= dd; acc.w *= dd;
  ((float4*)(agg + (size_t)node * HDIM))[q] = acc;
}

// ---- scalar-W fp32 GEMM ----
// out[n,96] = [A0|A1][n, 96*nkt] @ W[96*nkt, 96] + bias.
// Block 256 = 4 waves; tile 64 rows x 96 cols; lane = row, wave w owns
// cols [24w, 24w+24). W addresses are wave-uniform -> s_load on the scalar
// pipe (SGPR operand feeds v_fma directly); A read as 1 ds_read_b32/k at
// stride 64 (2-way aliasing = free). LDS = 24.6 KB, no pad needed.
// DUAL: second weight set reuses staged A; out1 = dis[r]*relu(z1).
template<bool RELU, bool DUAL>
__global__ __launch_bounds__(256) void gemm_k(
    const float* __restrict__ A0, const float* __restrict__ A1,
    const float* __restrict__ W0, const float* __restrict__ b0, float* __restrict__ out0,
    const float* __restrict__ W1, const float* __restrict__ b1, float* __restrict__ out1,
    const float* __restrict__ dis, int n, int nkt) {
  __shared__ float AsT[HDIM * 64];          // 24.6 KB, AsT[k][row]
  const int t = threadIdx.x;
  const int lane = t & 63;
  const int cbase = __builtin_amdgcn_readfirstlane((t >> 6) * 24);
  const int row0 = blockIdx.x * 64;
  const int r = row0 + lane;

  float acc0[24], acc1[24];
#pragma unroll
  for (int c = 0; c < 24; c++) acc0[c] = b0[cbase + c];
  if (DUAL) {
#pragma unroll
    for (int c = 0; c < 24; c++) acc1[c] = b1[cbase + c];
  }

  for (int kt = 0; kt < nkt; kt++) {
    const float* A = kt ? A1 : A0;
    __syncthreads();   // previous tile fully consumed
    // stage 64x96 tile transposed; lanes walk rows fastest -> conflict-free writes
    for (int idx = t; idx < 1536; idx += 256) {
      const int rr = idx & 63, q = idx >> 6;   // q = col-quad 0..23
      float4 v = make_float4(0.f, 0.f, 0.f, 0.f);
      if (row0 + rr < n) v = *(const float4*)(A + (size_t)(row0 + rr) * HDIM + 4 * q);
      AsT[(4 * q + 0) * 64 + rr] = v.x;
      AsT[(4 * q + 1) * 64 + rr] = v.y;
      AsT[(4 * q + 2) * 64 + rr] = v.z;
      AsT[(4 * q + 3) * 64 + rr] = v.w;
    }
    __syncthreads();
    const float* Wk0 = W0 + (size_t)kt * HDIM * HDIM + cbase;
    const float* Wk1 = DUAL ? (W1 + (size_t)kt * HDIM * HDIM + cbase) : nullptr;
#pragma unroll 4
    for (int k = 0; k < HDIM; k++) {
      const float xk = AsT[k * 64 + lane];
#pragma unroll
      for (int c = 0; c < 24; c++)
        acc0[c] = fmaf(xk, Wk0[k * HDIM + c], acc0[c]);
      if (DUAL) {
#pragma unroll
        for (int c = 0; c < 24; c++)
          acc1[c] = fmaf(xk, Wk1[k * HDIM + c], acc1[c]);
      }
    }
  }

  if (r < n) {
    float* o0 = out0 + (size_t)r * HDIM + cbase;
#pragma unroll
    for (int q = 0; q < 6; q++) {
      float4 o;
      o.x = RELU ? fmaxf(acc0[4*q+0], 0.f) : acc0[4*q+0];
      o.y = RELU ? fmaxf(acc0[4*q+1], 0.f) : acc0[4*q+1];
      o.z = RELU ? fmaxf(acc0[4*q+2], 0.f) : acc0[4*q+2];
      o.w = RELU ? fmaxf(acc0[4*q+3], 0.f) : acc0[4*q+3];
      *(float4*)(o0 + 4 * q) = o;
    }
    if (DUAL) {
      const float d = dis[r];
      float* o1 = out1 + (size_t)r * HDIM + cbase;
#pragma unroll
      for (int q = 0; q < 6; q++) {
        float4 p;
        p.x = d * fmaxf(acc1[4*q+0], 0.f);
        p.y = d * fmaxf(acc1[4*q+1], 0.f);
        p.z = d * fmaxf(acc1[4*q+2], 0.f);
        p.w = d * fmaxf(acc1[4*q+3], 0.f);
        *(float4*)(o1 + 4 * q) = p;
      }
    }
  }
}

extern "C" void kernel_launch(void* const* d_in, const int* in_sizes, int n_in,
                              void* d_out, int out_size, void* d_ws, size_t ws_size,
                              hipStream_t stream) {
  const float* x       = (const float*)d_in[0];
  const int*   edge    = (const int*)d_in[1];
  const float* W_local = (const float*)d_in[2];
  const float* b_local = (const float*)d_in[3];
  const float* W_g1    = (const float*)d_in[4];
  const float* b_g1    = (const float*)d_in[5];
  const float* W_g2    = (const float*)d_in[6];
  const float* b_g2    = (const float*)d_in[7];
  const float* W_fuse  = (const float*)d_in[8]; // [192, 96] row-major
  const float* b_fuse  = (const float*)d_in[9];
  float* out = (float*)d_out;

  const int n = in_sizes[0] / HDIM;
  const int e = in_sizes[1] / 2;
  const int* src = edge;
  const int* dst = edge + e;
  const int nb = (n + 1023) / 1024;

  char* ws = (char*)d_ws;
  auto alloc = [&](size_t bytes) { char* p = ws; ws += (bytes + 255) & ~(size_t)255; return p; };
  int*   indeg   = (int*)alloc((size_t)n * 4);
  float* dis     = (float*)alloc((size_t)n * 4);
  int*   offsets = (int*)alloc((size_t)(n + 1) * 4);
  int*   bsum    = (int*)alloc((size_t)nb * 4);
  int*   bbase   = (int*)alloc((size_t)nb * 4);
  int*   rank    = (int*)alloc((size_t)e * 4);
  int*   csr_src = (int*)alloc((size_t)e * 4);
  float* bufA    = (float*)alloc((size_t)n * HDIM * 4);   // ax / ag2
  float* bufB    = (float*)alloc((size_t)n * HDIM * 4);   // x' then local
  float* bufC    = (float*)alloc((size_t)n * HDIM * 4);   // g1' then g2

  zero_k<<<(n + 255) / 256, 256, 0, stream>>>(indeg, n);
  deg_rank_k<<<(e + 255) / 256, 256, 0, stream>>>(dst, indeg, rank, e);
  scan_a_k<<<nb, 1024, 0, stream>>>(indeg, bsum, n);
  scan_b_k<<<1, 1024, 0, stream>>>(bsum, bbase, offsets, nb, n);
  scan_c_k<<<nb, 1024, 0, stream>>>(indeg, bbase, offsets, dis, n);
  place_k<<<(e + 255) / 256, 256, 0, stream>>>(src, dst, rank, offsets, csr_src, e);

  const int ggrid = (n + 7) / 8;
  const int gb = (n + 63) / 64;

  // x' = dis·x  (bufB is free until the dual GEMM overwrites it)
  scale_k<<<(n * 24 + 255) / 256, 256, 0, stream>>>(x, dis, bufB, n);
  // ax = dis·(x'[d] + Σ x'[s])
  gather_k<<<ggrid, 192, 0, stream>>>(csr_src, offsets, dis, bufB, bufA, n);
  // local = relu(ax@W_local+b);  g1' = dis·relu(ax@W_g1+b)   (one A pass)
  gemm_k<true, true><<<gb, 256, 0, stream>>>(bufA, nullptr, W_local, b_local, bufB,
                                             W_g1, b_g1, bufC, dis, n, 1);
  // ag2 = dis·(g1'[d] + Σ g1'[s]);  g2 = relu(ag2@W_g2+b)
  gather_k<<<ggrid, 192, 0, stream>>>(csr_src, offsets, dis, bufC, bufA, n);
  gemm_k<true, false><<<gb, 256, 0, stream>>>(bufA, nullptr, W_g2, b_g2, bufC,
                                              nullptr, nullptr, nullptr, nullptr, n, 1);
  // out = [local | g2] @ W_fuse + b_fuse   (K=192: two 96-tiles)
  gemm_k<false, false><<<gb, 256, 0, stream>>>(bufB, bufC, W_fuse, b_fuse, out,
                                               nullptr, nullptr, nullptr, nullptr, n, 2);
}

// Round 10
// 349.465 us; speedup vs baseline: 1.0424x; 1.0424x over previous
//
#include <hip/hip_runtime.h>

#define HDIM 96
#define LSTR 104   // LDS row stride in bf16 elems (96 + 8 pad), 208 B, 16B-aligned

typedef __attribute__((ext_vector_type(8))) short bf16x8;   // 8 bf16 = 4 VGPRs
typedef __attribute__((ext_vector_type(4))) float f32x4;

__global__ void zero_k(int* __restrict__ p, int n) {
  int i = blockIdx.x * blockDim.x + threadIdx.x;
  if (i < n) p[i] = 0;
}

__global__ void deg_rank_k(const int* __restrict__ dst, int* __restrict__ indeg,
                           int* __restrict__ rank, int e) {
  int i = blockIdx.x * blockDim.x + threadIdx.x;
  if (i < e) rank[i] = atomicAdd(&indeg[dst[i]], 1);
}

__device__ __forceinline__ int wave_incl_scan(int v, int lane) {
#pragma unroll
  for (int off = 1; off < 64; off <<= 1) {
    int t = __shfl_up(v, off, 64);
    if (lane >= off) v += t;
  }
  return v;
}

__global__ __launch_bounds__(1024) void scan_a_k(const int* __restrict__ indeg,
                                                 int* __restrict__ bsum, int n) {
  const int tid = threadIdx.x;
  const int i = blockIdx.x * 1024 + tid;
  int v = (i < n) ? indeg[i] : 0;
#pragma unroll
  for (int off = 32; off; off >>= 1) v += __shfl_down(v, off, 64);
  __shared__ int ws[16];
  if ((tid & 63) == 0) ws[tid >> 6] = v;
  __syncthreads();
  if (tid < 16) {
    int s = ws[tid];
#pragma unroll
    for (int off = 8; off; off >>= 1) s += __shfl_down(s, off, 16);
    if (tid == 0) bsum[blockIdx.x] = s;
  }
}

__global__ __launch_bounds__(1024) void scan_b_k(const int* __restrict__ bsum,
                                                 int* __restrict__ bbase,
                                                 int* __restrict__ offsets, int nb, int n) {
  __shared__ int ws[16];
  const int tid = threadIdx.x, lane = tid & 63, w = tid >> 6;
  const int v = (tid < nb) ? bsum[tid] : 0;
  int incl = wave_incl_scan(v, lane);
  if (lane == 63) ws[w] = incl;
  __syncthreads();
  if (tid < 16) {
    int s = ws[tid];
#pragma unroll
    for (int off = 1; off < 16; off <<= 1) {
      int t = __shfl_up(s, off, 16);
      if (tid >= off) s += t;
    }
    ws[tid] = s;
  }
  __syncthreads();
  incl += (w > 0 ? ws[w - 1] : 0);
  if (tid < nb) bbase[tid] = incl - v;
  if (tid == 0) offsets[n] = ws[15];
}

__global__ __launch_bounds__(1024) void scan_c_k(const int* __restrict__ indeg,
                                                 const int* __restrict__ bbase,
                                                 int* __restrict__ offsets,
                                                 float* __restrict__ dis, int n) {
  __shared__ int ws[16];
  const int tid = threadIdx.x, lane = tid & 63, w = tid >> 6;
  const int i = blockIdx.x * 1024 + tid;
  const int v = (i < n) ? indeg[i] : 0;
  int incl = wave_incl_scan(v, lane);
  if (lane == 63) ws[w] = incl;
  __syncthreads();
  if (tid < 16) {
    int s = ws[tid];
#pragma unroll
    for (int off = 1; off < 16; off <<= 1) {
      int t = __shfl_up(s, off, 16);
      if (tid >= off) s += t;
    }
    ws[tid] = s;
  }
  __syncthreads();
  incl += (w > 0 ? ws[w - 1] : 0);
  if (i < n) {
    offsets[i] = bbase[blockIdx.x] + incl - v;
    dis[i] = rsqrtf((float)(1 + v));
  }
}

__global__ void place_k(const int* __restrict__ src, const int* __restrict__ dst,
                        const int* __restrict__ rank, const int* __restrict__ offsets,
                        int* __restrict__ csr_src, int e) {
  int i = blockIdx.x * blockDim.x + threadIdx.x;
  if (i >= e) return;
  int d = dst[i];
  atomicExch(&csr_src[offsets[d] + rank[i]], src[i]);
}

__global__ void scale_k(const float* __restrict__ x, const float* __restrict__ dis,
                        float* __restrict__ o, int n) {
  int t = blockIdx.x * blockDim.x + threadIdx.x;
  if (t >= n * 24) return;
  const float d = dis[t / 24];
  float4 v = ((const float4*)x)[t];
  v.x *= d; v.y *= d; v.z *= d; v.w *= d;
  ((float4*)o)[t] = v;
}

// agg[d,:] = dis[d] * ( hp[d,:] + sum_{s->d} hp[s,:] )   (hp pre-scaled dis*h)
__global__ __launch_bounds__(192) void gather_k(
    const int* __restrict__ csr_src, const int* __restrict__ offsets,
    const float* __restrict__ dis, const float* __restrict__ hp,
    float* __restrict__ agg, int n) {
  const int tid  = threadIdx.x;
  const int node = blockIdx.x * 8 + tid / 24;
  const int q    = tid % 24;
  if (node >= n) return;
  float4 acc = ((const float4*)(hp + (size_t)node * HDIM))[q];
  int i = offsets[node];
  const int end = offsets[node + 1];
  for (; i + 3 < end; i += 4) {
    const int s0 = csr_src[i], s1 = csr_src[i + 1], s2 = csr_src[i + 2], s3 = csr_src[i + 3];
    const float4 v0 = ((const float4*)(hp + (size_t)s0 * HDIM))[q];
    const float4 v1 = ((const float4*)(hp + (size_t)s1 * HDIM))[q];
    const float4 v2 = ((const float4*)(hp + (size_t)s2 * HDIM))[q];
    const float4 v3 = ((const float4*)(hp + (size_t)s3 * HDIM))[q];
    acc.x += v0.x + v1.x + v2.x + v3.x;
    acc.y += v0.y + v1.y + v2.y + v3.y;
    acc.z += v0.z + v1.z + v2.z + v3.z;
    acc.w += v0.w + v1.w + v2.w + v3.w;
  }
  for (; i < end; i++) {
    const int s0 = csr_src[i];
    const float4 v0 = ((const float4*)(hp + (size_t)s0 * HDIM))[q];
    acc.x += v0.x; acc.y += v0.y; acc.z += v0.z; acc.w += v0.w;
  }
  const float dd = dis[node];
  acc.x *= dd; acc.y *= dd; acc.z *= dd; acc.w *= dd;
  ((float4*)(agg + (size_t)node * HDIM))[q] = acc;
}

// fp32 -> (hi, lo) truncated bf16 pair; x ~= hi + lo with ~2^-16 rel error
__device__ __forceinline__ void split2(float x, unsigned short& hi, unsigned short& lo) {
  const unsigned u = __float_as_uint(x);
  hi = (unsigned short)(u >> 16);
  const float xhi = __uint_as_float(u & 0xffff0000u);
  lo = (unsigned short)(__float_as_uint(x - xhi) >> 16);
}

// ---- split-bf16 MFMA GEMM ----
// out[M,96] = [A0|A1][M, 96*nkt] @ W[96*nkt, 96] + bias, fp32-accurate via
// 3-term split: Ahi*Whi + Ahi*Wlo + Alo*Whi  (error ~2^-16, vs thr 4.7e-3).
// Block 256 thr = 4 waves; tile 64 rows; wave wv -> rows [16wv,16wv+16) x 96.
// Staging converts fp32->bf16 hi/lo into LDS (A row-major k-contig; W
// TRANSPOSED [n][k] so B-frags are b128). Frag layouts (m89/m120-verified):
// A: m=lane&15, k=quad*8+j; B: n=lane&15, same k; D: col=lane&15, row=quad*4+r.
// LDS = 66.5 KB -> 2 blocks/CU; grid 782.
template<bool RELU, bool SCALE>
__global__ __launch_bounds__(256) void gemm_mfma_k(
    const float* __restrict__ A0, const float* __restrict__ A1,
    const float* __restrict__ W, const float* __restrict__ bias,
    const float* __restrict__ dis, float* __restrict__ out, int M, int nkt) {
  __shared__ __align__(16) unsigned short Ah[64 * LSTR], Al[64 * LSTR];
  __shared__ __align__(16) unsigned short Wh[96 * LSTR], Wl[96 * LSTR];
  const int t = threadIdx.x;
  const int lane = t & 63, wv = t >> 6;
  const int m = lane & 15, quad = lane >> 4;
  const int row0 = blockIdx.x * 64;

  f32x4 acc[6];
#pragma unroll
  for (int c = 0; c < 6; c++) acc[c] = (f32x4){0.f, 0.f, 0.f, 0.f};

  for (int kt = 0; kt < nkt; kt++) {
    const float* A = kt ? A1 : A0;
    if (kt) __syncthreads();
    // stage A: 64 rows x 96 k, split hi/lo  (coalesced float4 reads)
    for (int u = t; u < 1536; u += 256) {
      const int r = u / 24, kq = u % 24;
      float4 v = make_float4(0.f, 0.f, 0.f, 0.f);
      if (row0 + r < M) v = *(const float4*)(A + (size_t)(row0 + r) * HDIM + 4 * kq);
      ushort4 h, l;
      split2(v.x, h.x, l.x); split2(v.y, h.y, l.y);
      split2(v.z, h.z, l.z); split2(v.w, h.w, l.w);
      *(ushort4*)(&Ah[r * LSTR + 4 * kq]) = h;
      *(ushort4*)(&Al[r * LSTR + 4 * kq]) = l;
    }
    // stage W transposed: Wt[n][k]; nn fastest -> coalesced global reads
    const float* Wb = W + (size_t)kt * HDIM * HDIM;
    for (int u = t; u < 2304; u += 256) {
      const int nn = u % 96, kq = u / 96;
      const float* wp = Wb + (size_t)(4 * kq) * HDIM + nn;
      ushort4 h, l;
      split2(wp[0],       h.x, l.x);
      split2(wp[HDIM],    h.y, l.y);
      split2(wp[2*HDIM],  h.z, l.z);
      split2(wp[3*HDIM],  h.w, l.w);
      *(ushort4*)(&Wh[nn * LSTR + 4 * kq]) = h;
      *(ushort4*)(&Wl[nn * LSTR + 4 * kq]) = l;
    }
    __syncthreads();
#pragma unroll
    for (int kc = 0; kc < 3; kc++) {
      const int ko = 32 * kc + 8 * quad;
      const bf16x8 ah = *(const bf16x8*)(&Ah[(16 * wv + m) * LSTR + ko]);
      const bf16x8 al = *(const bf16x8*)(&Al[(16 * wv + m) * LSTR + ko]);
#pragma unroll
      for (int c = 0; c < 6; c++) {
        const bf16x8 wh = *(const bf16x8*)(&Wh[(16 * c + m) * LSTR + ko]);
        const bf16x8 wl = *(const bf16x8*)(&Wl[(16 * c + m) * LSTR + ko]);
        acc[c] = __builtin_amdgcn_mfma_f32_16x16x32_bf16(ah, wh, acc[c], 0, 0, 0);
        acc[c] = __builtin_amdgcn_mfma_f32_16x16x32_bf16(ah, wl, acc[c], 0, 0, 0);
        acc[c] = __builtin_amdgcn_mfma_f32_16x16x32_bf16(al, wh, acc[c], 0, 0, 0);
      }
    }
  }

  // epilogue: D col=lane&15, row(within 16) = quad*4 + r
  const int rbase = row0 + 16 * wv + 4 * quad;
  float dv[4];
  if (SCALE) {
#pragma unroll
    for (int r = 0; r < 4; r++) dv[r] = (rbase + r < M) ? dis[rbase + r] : 0.f;
  }
#pragma unroll
  for (int c = 0; c < 6; c++) {
    const int col = 16 * c + m;
    const float bv = bias[col];
#pragma unroll
    for (int r = 0; r < 4; r++) {
      const int row = rbase + r;
      if (row < M) {
        float v = acc[c][r] + bv;
        if (RELU) v = fmaxf(v, 0.f);
        if (SCALE) v *= dv[r];
        out[(size_t)row * HDIM + col] = v;
      }
    }
  }
}

extern "C" void kernel_launch(void* const* d_in, const int* in_sizes, int n_in,
                              void* d_out, int out_size, void* d_ws, size_t ws_size,
                              hipStream_t stream) {
  const float* x       = (const float*)d_in[0];
  const int*   edge    = (const int*)d_in[1];
  const float* W_local = (const float*)d_in[2];
  const float* b_local = (const float*)d_in[3];
  const float* W_g1    = (const float*)d_in[4];
  const float* b_g1    = (const float*)d_in[5];
  const float* W_g2    = (const float*)d_in[6];
  const float* b_g2    = (const float*)d_in[7];
  const float* W_fuse  = (const float*)d_in[8]; // [192, 96] row-major
  const float* b_fuse  = (const float*)d_in[9];
  float* out = (float*)d_out;

  const int n = in_sizes[0] / HDIM;
  const int e = in_sizes[1] / 2;
  const int* src = edge;
  const int* dst = edge + e;
  const int nb = (n + 1023) / 1024;

  char* ws = (char*)d_ws;
  auto alloc = [&](size_t bytes) { char* p = ws; ws += (bytes + 255) & ~(size_t)255; return p; };
  int*   indeg   = (int*)alloc((size_t)n * 4);
  float* dis     = (float*)alloc((size_t)n * 4);
  int*   offsets = (int*)alloc((size_t)(n + 1) * 4);
  int*   bsum    = (int*)alloc((size_t)nb * 4);
  int*   bbase   = (int*)alloc((size_t)nb * 4);
  int*   rank    = (int*)alloc((size_t)e * 4);
  int*   csr_src = (int*)alloc((size_t)e * 4);
  float* bufA    = (float*)alloc((size_t)n * HDIM * 4);   // ax / ag2
  float* bufB    = (float*)alloc((size_t)n * HDIM * 4);   // x' then local
  float* bufC    = (float*)alloc((size_t)n * HDIM * 4);   // g1' then g2

  zero_k<<<(n + 255) / 256, 256, 0, stream>>>(indeg, n);
  deg_rank_k<<<(e + 255) / 256, 256, 0, stream>>>(dst, indeg, rank, e);
  scan_a_k<<<nb, 1024, 0, stream>>>(indeg, bsum, n);
  scan_b_k<<<1, 1024, 0, stream>>>(bsum, bbase, offsets, nb, n);
  scan_c_k<<<nb, 1024, 0, stream>>>(indeg, bbase, offsets, dis, n);
  place_k<<<(e + 255) / 256, 256, 0, stream>>>(src, dst, rank, offsets, csr_src, e);

  const int ggrid = (n + 7) / 8;
  const int gb = (n + 63) / 64;

  // x' = dis·x  (bufB is free until the local GEMM overwrites it)
  scale_k<<<(n * 24 + 255) / 256, 256, 0, stream>>>(x, dis, bufB, n);
  // ax = dis·(x'[d] + Σ x'[s])
  gather_k<<<ggrid, 192, 0, stream>>>(csr_src, offsets, dis, bufB, bufA, n);
  // local = relu(ax@W_local+b);  g1' = dis·relu(ax@W_g1+b)
  gemm_mfma_k<true, false><<<gb, 256, 0, stream>>>(bufA, nullptr, W_local, b_local, nullptr, bufB, n, 1);
  gemm_mfma_k<true, true ><<<gb, 256, 0, stream>>>(bufA, nullptr, W_g1, b_g1, dis, bufC, n, 1);
  // ag2 = dis·(g1'[d] + Σ g1'[s]);  g2 = relu(ag2@W_g2+b)
  gather_k<<<ggrid, 192, 0, stream>>>(csr_src, offsets, dis, bufC, bufA, n);
  gemm_mfma_k<true, false><<<gb, 256, 0, stream>>>(bufA, nullptr, W_g2, b_g2, nullptr, bufC, n, 1);
  // out = [local | g2] @ W_fuse + b_fuse   (K=192: two 96-tiles)
  gemm_mfma_k<false, false><<<gb, 256, 0, stream>>>(bufB, bufC, W_fuse, b_fuse, nullptr, out, n, 2);
}

// Round 11
// 317.277 us; speedup vs baseline: 1.1482x; 1.1015x over previous
//
#include <hip/hip_runtime.h>

#define HDIM 96
#define LSTR 104   // LDS row stride in bf16 elems (96 + 8 pad), 208 B, 16B-aligned

typedef __attribute__((ext_vector_type(8))) short bf16x8;   // 8 bf16 = 4 VGPRs
typedef __attribute__((ext_vector_type(4))) float f32x4;

__device__ __forceinline__ unsigned short bf16rne(float x) {
  const unsigned u = __float_as_uint(x);
  return (unsigned short)((u + 0x7fff + ((u >> 16) & 1)) >> 16);
}

__global__ void zero_k(int* __restrict__ p, int n) {
  int i = blockIdx.x * blockDim.x + threadIdx.x;
  if (i < n) p[i] = 0;
}

__global__ void deg_rank_k(const int* __restrict__ dst, int* __restrict__ indeg,
                           int* __restrict__ rank, int e) {
  int i = blockIdx.x * blockDim.x + threadIdx.x;
  if (i < e) rank[i] = atomicAdd(&indeg[dst[i]], 1);
}

__device__ __forceinline__ int wave_incl_scan(int v, int lane) {
#pragma unroll
  for (int off = 1; off < 64; off <<= 1) {
    int t = __shfl_up(v, off, 64);
    if (lane >= off) v += t;
  }
  return v;
}

__global__ __launch_bounds__(1024) void scan_a_k(const int* __restrict__ indeg,
                                                 int* __restrict__ bsum, int n) {
  const int tid = threadIdx.x;
  const int i = blockIdx.x * 1024 + tid;
  int v = (i < n) ? indeg[i] : 0;
#pragma unroll
  for (int off = 32; off; off >>= 1) v += __shfl_down(v, off, 64);
  __shared__ int ws[16];
  if ((tid & 63) == 0) ws[tid >> 6] = v;
  __syncthreads();
  if (tid < 16) {
    int s = ws[tid];
#pragma unroll
    for (int off = 8; off; off >>= 1) s += __shfl_down(s, off, 16);
    if (tid == 0) bsum[blockIdx.x] = s;
  }
}

__global__ __launch_bounds__(1024) void scan_b_k(const int* __restrict__ bsum,
                                                 int* __restrict__ bbase,
                                                 int* __restrict__ offsets, int nb, int n) {
  __shared__ int ws[16];
  const int tid = threadIdx.x, lane = tid & 63, w = tid >> 6;
  const int v = (tid < nb) ? bsum[tid] : 0;
  int incl = wave_incl_scan(v, lane);
  if (lane == 63) ws[w] = incl;
  __syncthreads();
  if (tid < 16) {
    int s = ws[tid];
#pragma unroll
    for (int off = 1; off < 16; off <<= 1) {
      int t = __shfl_up(s, off, 16);
      if (tid >= off) s += t;
    }
    ws[tid] = s;
  }
  __syncthreads();
  incl += (w > 0 ? ws[w - 1] : 0);
  if (tid < nb) bbase[tid] = incl - v;
  if (tid == 0) offsets[n] = ws[15];
}

__global__ __launch_bounds__(1024) void scan_c_k(const int* __restrict__ indeg,
                                                 const int* __restrict__ bbase,
                                                 int* __restrict__ offsets,
                                                 float* __restrict__ dis, int n) {
  __shared__ int ws[16];
  const int tid = threadIdx.x, lane = tid & 63, w = tid >> 6;
  const int i = blockIdx.x * 1024 + tid;
  const int v = (i < n) ? indeg[i] : 0;
  int incl = wave_incl_scan(v, lane);
  if (lane == 63) ws[w] = incl;
  __syncthreads();
  if (tid < 16) {
    int s = ws[tid];
#pragma unroll
    for (int off = 1; off < 16; off <<= 1) {
      int t = __shfl_up(s, off, 16);
      if (tid >= off) s += t;
    }
    ws[tid] = s;
  }
  __syncthreads();
  incl += (w > 0 ? ws[w - 1] : 0);
  if (i < n) {
    offsets[i] = bbase[blockIdx.x] + incl - v;
    dis[i] = rsqrtf((float)(1 + v));
  }
}

__global__ void place_k(const int* __restrict__ src, const int* __restrict__ dst,
                        const int* __restrict__ rank, const int* __restrict__ offsets,
                        int* __restrict__ csr_src, int e) {
  int i = blockIdx.x * blockDim.x + threadIdx.x;
  if (i >= e) return;
  int d = dst[i];
  atomicExch(&csr_src[offsets[d] + rank[i]], src[i]);
}

// o[i,:] = bf16( dis[i] * x[i,:] )   (messages stored half-width)
__global__ void scale_bf16_k(const float* __restrict__ x, const float* __restrict__ dis,
                             unsigned short* __restrict__ o, int n) {
  int t = blockIdx.x * blockDim.x + threadIdx.x;
  if (t >= n * 24) return;
  const float d = dis[t / 24];
  float4 v = ((const float4*)x)[t];
  ushort4 h;
  h.x = bf16rne(v.x * d); h.y = bf16rne(v.y * d);
  h.z = bf16rne(v.z * d); h.w = bf16rne(v.w * d);
  ((ushort4*)o)[t] = h;
}

__device__ __forceinline__ void acc8(float* a, uint4 p) {
  a[0] += __uint_as_float(p.x << 16);
  a[1] += __uint_as_float(p.x & 0xffff0000u);
  a[2] += __uint_as_float(p.y << 16);
  a[3] += __uint_as_float(p.y & 0xffff0000u);
  a[4] += __uint_as_float(p.z << 16);
  a[5] += __uint_as_float(p.z & 0xffff0000u);
  a[6] += __uint_as_float(p.w << 16);
  a[7] += __uint_as_float(p.w & 0xffff0000u);
}

// agg[d,:] = dis[d] * ( hp[d,:] + sum_{s->d} hp[s,:] )   (hp bf16, agg fp32)
// 12 lanes per node, 8 bf16 (one uint4) each; block 192 -> 16 nodes.
__global__ __launch_bounds__(192) void gather_k(
    const int* __restrict__ csr_src, const int* __restrict__ offsets,
    const float* __restrict__ dis, const unsigned short* __restrict__ hp,
    float* __restrict__ agg, int n) {
  const int tid  = threadIdx.x;
  const int node = blockIdx.x * 16 + tid / 12;
  const int q    = tid % 12;
  if (node >= n) return;
  float a[8] = {0.f, 0.f, 0.f, 0.f, 0.f, 0.f, 0.f, 0.f};
  acc8(a, ((const uint4*)(hp + (size_t)node * HDIM))[q]);   // self term
  int i = offsets[node];
  const int end = offsets[node + 1];
  for (; i + 3 < end; i += 4) {
    const int s0 = csr_src[i], s1 = csr_src[i + 1], s2 = csr_src[i + 2], s3 = csr_src[i + 3];
    const uint4 p0 = ((const uint4*)(hp + (size_t)s0 * HDIM))[q];
    const uint4 p1 = ((const uint4*)(hp + (size_t)s1 * HDIM))[q];
    const uint4 p2 = ((const uint4*)(hp + (size_t)s2 * HDIM))[q];
    const uint4 p3 = ((const uint4*)(hp + (size_t)s3 * HDIM))[q];
    acc8(a, p0); acc8(a, p1); acc8(a, p2); acc8(a, p3);
  }
  for (; i < end; i++) {
    acc8(a, ((const uint4*)(hp + (size_t)csr_src[i] * HDIM))[q]);
  }
  const float dd = dis[node];
  float4 o0, o1;
  o0.x = a[0] * dd; o0.y = a[1] * dd; o0.z = a[2] * dd; o0.w = a[3] * dd;
  o1.x = a[4] * dd; o1.y = a[5] * dd; o1.z = a[6] * dd; o1.w = a[7] * dd;
  float* orow = agg + (size_t)node * HDIM + 8 * q;
  *(float4*)(orow)     = o0;
  *(float4*)(orow + 4) = o1;
}

// fp32 -> (hi, lo) truncated bf16 pair; x ~= hi + lo with ~2^-16 rel error
__device__ __forceinline__ void split2(float x, unsigned short& hi, unsigned short& lo) {
  const unsigned u = __float_as_uint(x);
  hi = (unsigned short)(u >> 16);
  const float xhi = __uint_as_float(u & 0xffff0000u);
  lo = (unsigned short)(__float_as_uint(x - xhi) >> 16);
}

// ---- split-bf16 MFMA GEMM ----
// out[M,96] = [A0|A1][M, 96*nkt] @ W[96*nkt, 96] + bias, fp32-accurate via
// 3-term split: Ahi*Whi + Ahi*Wlo + Alo*Whi.
// Block 256 thr = 4 waves; tile 64 rows; wave wv -> rows [16wv,16wv+16) x 96.
// BF16OUT: epilogue emits RNE bf16 (pre-scaled message buffer for next hop).
template<bool RELU, bool SCALE, bool BF16OUT>
__global__ __launch_bounds__(256) void gemm_mfma_k(
    const float* __restrict__ A0, const float* __restrict__ A1,
    const float* __restrict__ W, const float* __restrict__ bias,
    const float* __restrict__ dis, void* __restrict__ outv, int M, int nkt) {
  __shared__ __align__(16) unsigned short Ah[64 * LSTR], Al[64 * LSTR];
  __shared__ __align__(16) unsigned short Wh[96 * LSTR], Wl[96 * LSTR];
  const int t = threadIdx.x;
  const int lane = t & 63, wv = t >> 6;
  const int m = lane & 15, quad = lane >> 4;
  const int row0 = blockIdx.x * 64;

  f32x4 acc[6];
#pragma unroll
  for (int c = 0; c < 6; c++) acc[c] = (f32x4){0.f, 0.f, 0.f, 0.f};

  for (int kt = 0; kt < nkt; kt++) {
    const float* A = kt ? A1 : A0;
    if (kt) __syncthreads();
    // stage A: 64 rows x 96 k, split hi/lo  (coalesced float4 reads)
    for (int u = t; u < 1536; u += 256) {
      const int r = u / 24, kq = u % 24;
      float4 v = make_float4(0.f, 0.f, 0.f, 0.f);
      if (row0 + r < M) v = *(const float4*)(A + (size_t)(row0 + r) * HDIM + 4 * kq);
      ushort4 h, l;
      split2(v.x, h.x, l.x); split2(v.y, h.y, l.y);
      split2(v.z, h.z, l.z); split2(v.w, h.w, l.w);
      *(ushort4*)(&Ah[r * LSTR + 4 * kq]) = h;
      *(ushort4*)(&Al[r * LSTR + 4 * kq]) = l;
    }
    // stage W transposed: Wt[n][k]; nn fastest -> coalesced global reads
    const float* Wb = W + (size_t)kt * HDIM * HDIM;
    for (int u = t; u < 2304; u += 256) {
      const int nn = u % 96, kq = u / 96;
      const float* wp = Wb + (size_t)(4 * kq) * HDIM + nn;
      ushort4 h, l;
      split2(wp[0],       h.x, l.x);
      split2(wp[HDIM],    h.y, l.y);
      split2(wp[2*HDIM],  h.z, l.z);
      split2(wp[3*HDIM],  h.w, l.w);
      *(ushort4*)(&Wh[nn * LSTR + 4 * kq]) = h;
      *(ushort4*)(&Wl[nn * LSTR + 4 * kq]) = l;
    }
    __syncthreads();
#pragma unroll
    for (int kc = 0; kc < 3; kc++) {
      const int ko = 32 * kc + 8 * quad;
      const bf16x8 ah = *(const bf16x8*)(&Ah[(16 * wv + m) * LSTR + ko]);
      const bf16x8 al = *(const bf16x8*)(&Al[(16 * wv + m) * LSTR + ko]);
#pragma unroll
      for (int c = 0; c < 6; c++) {
        const bf16x8 wh = *(const bf16x8*)(&Wh[(16 * c + m) * LSTR + ko]);
        const bf16x8 wl = *(const bf16x8*)(&Wl[(16 * c + m) * LSTR + ko]);
        acc[c] = __builtin_amdgcn_mfma_f32_16x16x32_bf16(ah, wh, acc[c], 0, 0, 0);
        acc[c] = __builtin_amdgcn_mfma_f32_16x16x32_bf16(ah, wl, acc[c], 0, 0, 0);
        acc[c] = __builtin_amdgcn_mfma_f32_16x16x32_bf16(al, wh, acc[c], 0, 0, 0);
      }
    }
  }

  // epilogue: D col=lane&15, row(within 16) = quad*4 + r
  const int rbase = row0 + 16 * wv + 4 * quad;
  float dv[4];
  if (SCALE) {
#pragma unroll
    for (int r = 0; r < 4; r++) dv[r] = (rbase + r < M) ? dis[rbase + r] : 0.f;
  }
#pragma unroll
  for (int c = 0; c < 6; c++) {
    const int col = 16 * c + m;
    const float bv = bias[col];
#pragma unroll
    for (int r = 0; r < 4; r++) {
      const int row = rbase + r;
      if (row < M) {
        float v = acc[c][r] + bv;
        if (RELU) v = fmaxf(v, 0.f);
        if (SCALE) v *= dv[r];
        if (BF16OUT)
          ((unsigned short*)outv)[(size_t)row * HDIM + col] = bf16rne(v);
        else
          ((float*)outv)[(size_t)row * HDIM + col] = v;
      }
    }
  }
}

extern "C" void kernel_launch(void* const* d_in, const int* in_sizes, int n_in,
                              void* d_out, int out_size, void* d_ws, size_t ws_size,
                              hipStream_t stream) {
  const float* x       = (const float*)d_in[0];
  const int*   edge    = (const int*)d_in[1];
  const float* W_local = (const float*)d_in[2];
  const float* b_local = (const float*)d_in[3];
  const float* W_g1    = (const float*)d_in[4];
  const float* b_g1    = (const float*)d_in[5];
  const float* W_g2    = (const float*)d_in[6];
  const float* b_g2    = (const float*)d_in[7];
  const float* W_fuse  = (const float*)d_in[8]; // [192, 96] row-major
  const float* b_fuse  = (const float*)d_in[9];
  float* out = (float*)d_out;

  const int n = in_sizes[0] / HDIM;
  const int e = in_sizes[1] / 2;
  const int* src = edge;
  const int* dst = edge + e;
  const int nb = (n + 1023) / 1024;

  char* ws = (char*)d_ws;
  auto alloc = [&](size_t bytes) { char* p = ws; ws += (bytes + 255) & ~(size_t)255; return p; };
  int*   indeg   = (int*)alloc((size_t)n * 4);
  float* dis     = (float*)alloc((size_t)n * 4);
  int*   offsets = (int*)alloc((size_t)(n + 1) * 4);
  int*   bsum    = (int*)alloc((size_t)nb * 4);
  int*   bbase   = (int*)alloc((size_t)nb * 4);
  int*   rank    = (int*)alloc((size_t)e * 4);
  int*   csr_src = (int*)alloc((size_t)e * 4);
  float* bufA    = (float*)alloc((size_t)n * HDIM * 4);       // ax / ag2 (fp32)
  float* bufB    = (float*)alloc((size_t)n * HDIM * 4);       // x'(bf16) then local(fp32)
  float* bufC    = (float*)alloc((size_t)n * HDIM * 4);       // g1'(bf16) then g2(fp32)
  unsigned short* bufB16 = (unsigned short*)bufB;
  unsigned short* bufC16 = (unsigned short*)bufC;

  zero_k<<<(n + 255) / 256, 256, 0, stream>>>(indeg, n);
  deg_rank_k<<<(e + 255) / 256, 256, 0, stream>>>(dst, indeg, rank, e);
  scan_a_k<<<nb, 1024, 0, stream>>>(indeg, bsum, n);
  scan_b_k<<<1, 1024, 0, stream>>>(bsum, bbase, offsets, nb, n);
  scan_c_k<<<nb, 1024, 0, stream>>>(indeg, bbase, offsets, dis, n);
  place_k<<<(e + 255) / 256, 256, 0, stream>>>(src, dst, rank, offsets, csr_src, e);

  const int ggrid = (n + 15) / 16;
  const int gb = (n + 63) / 64;

  // x' = bf16(dis·x)
  scale_bf16_k<<<(n * 24 + 255) / 256, 256, 0, stream>>>(x, dis, bufB16, n);
  // ax = dis·(x'[d] + Σ x'[s])   (fp32 accumulate)
  gather_k<<<ggrid, 192, 0, stream>>>(csr_src, offsets, dis, bufB16, bufA, n);
  // local = relu(ax@W_local+b)  (fp32);  g1' = bf16(dis·relu(ax@W_g1+b))
  gemm_mfma_k<true, false, false><<<gb, 256, 0, stream>>>(bufA, nullptr, W_local, b_local, nullptr, bufB, n, 1);
  gemm_mfma_k<true, true,  true ><<<gb, 256, 0, stream>>>(bufA, nullptr, W_g1, b_g1, dis, bufC16, n, 1);
  // ag2 = dis·(g1'[d] + Σ g1'[s]);  g2 = relu(ag2@W_g2+b)  (fp32)
  gather_k<<<ggrid, 192, 0, stream>>>(csr_src, offsets, dis, bufC16, bufA, n);
  gemm_mfma_k<true, false, false><<<gb, 256, 0, stream>>>(bufA, nullptr, W_g2, b_g2, nullptr, bufC, n, 1);
  // out = [local | g2] @ W_fuse + b_fuse   (K=192: two 96-tiles)
  gemm_mfma_k<false, false, false><<<gb, 256, 0, stream>>>(bufB, bufC, W_fuse, b_fuse, nullptr, out, n, 2);
}

// Round 12
// 301.734 us; speedup vs baseline: 1.2073x; 1.0515x over previous
//
#include <hip/hip_runtime.h>

#define HDIM 96
#define LSTR 104   // LDS row stride in bf16 elems (96 + 8 pad); 208 B = 13*16 (16B-aligned rows)

typedef __attribute__((ext_vector_type(8))) short bf16x8;   // 8 bf16 = 4 VGPRs
typedef __attribute__((ext_vector_type(4))) float f32x4;

__device__ __forceinline__ unsigned short bf16rne(float x) {
  const unsigned u = __float_as_uint(x);
  return (unsigned short)((u + 0x7fff + ((u >> 16) & 1)) >> 16);
}

// fp32 -> (hi, lo) truncated bf16 pair; x ~= hi + lo with ~2^-16 rel error
__device__ __forceinline__ void split2(float x, unsigned short& hi, unsigned short& lo) {
  const unsigned u = __float_as_uint(x);
  hi = (unsigned short)(u >> 16);
  const float xhi = __uint_as_float(u & 0xffff0000u);
  lo = (unsigned short)(__float_as_uint(x - xhi) >> 16);
}

__global__ void zero_k(int* __restrict__ p, int n) {
  int i = blockIdx.x * blockDim.x + threadIdx.x;
  if (i < n) p[i] = 0;
}

__global__ void deg_rank_k(const int* __restrict__ dst, int* __restrict__ indeg,
                           int* __restrict__ rank, int e) {
  int i = blockIdx.x * blockDim.x + threadIdx.x;
  if (i < e) rank[i] = atomicAdd(&indeg[dst[i]], 1);
}

__device__ __forceinline__ int wave_incl_scan(int v, int lane) {
#pragma unroll
  for (int off = 1; off < 64; off <<= 1) {
    int t = __shfl_up(v, off, 64);
    if (lane >= off) v += t;
  }
  return v;
}

__global__ __launch_bounds__(1024) void scan_a_k(const int* __restrict__ indeg,
                                                 int* __restrict__ bsum, int n) {
  const int tid = threadIdx.x;
  const int i = blockIdx.x * 1024 + tid;
  int v = (i < n) ? indeg[i] : 0;
#pragma unroll
  for (int off = 32; off; off >>= 1) v += __shfl_down(v, off, 64);
  __shared__ int ws[16];
  if ((tid & 63) == 0) ws[tid >> 6] = v;
  __syncthreads();
  if (tid < 16) {
    int s = ws[tid];
#pragma unroll
    for (int off = 8; off; off >>= 1) s += __shfl_down(s, off, 16);
    if (tid == 0) bsum[blockIdx.x] = s;
  }
}

__global__ __launch_bounds__(1024) void scan_b_k(const int* __restrict__ bsum,
                                                 int* __restrict__ bbase,
                                                 int* __restrict__ offsets, int nb, int n) {
  __shared__ int ws[16];
  const int tid = threadIdx.x, lane = tid & 63, w = tid >> 6;
  const int v = (tid < nb) ? bsum[tid] : 0;
  int incl = wave_incl_scan(v, lane);
  if (lane == 63) ws[w] = incl;
  __syncthreads();
  if (tid < 16) {
    int s = ws[tid];
#pragma unroll
    for (int off = 1; off < 16; off <<= 1) {
      int t = __shfl_up(s, off, 16);
      if (tid >= off) s += t;
    }
    ws[tid] = s;
  }
  __syncthreads();
  incl += (w > 0 ? ws[w - 1] : 0);
  if (tid < nb) bbase[tid] = incl - v;
  if (tid == 0) offsets[n] = ws[15];
}

__global__ __launch_bounds__(1024) void scan_c_k(const int* __restrict__ indeg,
                                                 const int* __restrict__ bbase,
                                                 int* __restrict__ offsets,
                                                 float* __restrict__ dis, int n) {
  __shared__ int ws[16];
  const int tid = threadIdx.x, lane = tid & 63, w = tid >> 6;
  const int i = blockIdx.x * 1024 + tid;
  const int v = (i < n) ? indeg[i] : 0;
  int incl = wave_incl_scan(v, lane);
  if (lane == 63) ws[w] = incl;
  __syncthreads();
  if (tid < 16) {
    int s = ws[tid];
#pragma unroll
    for (int off = 1; off < 16; off <<= 1) {
      int t = __shfl_up(s, off, 16);
      if (tid >= off) s += t;
    }
    ws[tid] = s;
  }
  __syncthreads();
  incl += (w > 0 ? ws[w - 1] : 0);
  if (i < n) {
    offsets[i] = bbase[blockIdx.x] + incl - v;
    dis[i] = rsqrtf((float)(1 + v));
  }
}

__global__ void place_k(const int* __restrict__ src, const int* __restrict__ dst,
                        const int* __restrict__ rank, const int* __restrict__ offsets,
                        int* __restrict__ csr_src, int e) {
  int i = blockIdx.x * blockDim.x + threadIdx.x;
  if (i >= e) return;
  int d = dst[i];
  atomicExch(&csr_src[offsets[d] + rank[i]], src[i]);
}

// Pre-split ALL weights once into bf16 hi/lo, B-fragment-ready [n][k] layout.
// 5 tiles of 96x96: 0=W_local, 1=W_g1, 2=W_g2, 3=W_fuse[0:96], 4=W_fuse[96:192].
__global__ void split_w_k(const float* __restrict__ W0, const float* __restrict__ W1,
                          const float* __restrict__ W2, const float* __restrict__ W3,
                          unsigned short* __restrict__ dH, unsigned short* __restrict__ dL) {
  const int t = blockIdx.x * blockDim.x + threadIdx.x;
  if (t >= 5 * 9216) return;
  const int tile = t / 9216, r = t % 9216;
  const int nn = r / 96, k = r % 96;
  const float* W = (tile == 0) ? W0 : (tile == 1) ? W1 : (tile == 2) ? W2 : W3;
  const int row = (tile == 4) ? 96 + k : k;
  unsigned short h, l;
  split2(W[row * 96 + nn], h, l);
  dH[t] = h;
  dL[t] = l;
}

// o[i,:] = bf16( dis[i] * x[i,:] )   (messages stored half-width)
__global__ void scale_bf16_k(const float* __restrict__ x, const float* __restrict__ dis,
                             unsigned short* __restrict__ o, int n) {
  int t = blockIdx.x * blockDim.x + threadIdx.x;
  if (t >= n * 24) return;
  const float d = dis[t / 24];
  float4 v = ((const float4*)x)[t];
  ushort4 h;
  h.x = bf16rne(v.x * d); h.y = bf16rne(v.y * d);
  h.z = bf16rne(v.z * d); h.w = bf16rne(v.w * d);
  ((ushort4*)o)[t] = h;
}

__device__ __forceinline__ void acc8(float* a, uint4 p) {
  a[0] += __uint_as_float(p.x << 16);
  a[1] += __uint_as_float(p.x & 0xffff0000u);
  a[2] += __uint_as_float(p.y << 16);
  a[3] += __uint_as_float(p.y & 0xffff0000u);
  a[4] += __uint_as_float(p.z << 16);
  a[5] += __uint_as_float(p.z & 0xffff0000u);
  a[6] += __uint_as_float(p.w << 16);
  a[7] += __uint_as_float(p.w & 0xffff0000u);
}

// agg = dis[d]*(hp[d] + sum hp[s]); OUTPUT = split bf16 hi/lo pair (MFMA-A-ready).
// 12 lanes per node, 8 bf16 (one uint4) each; block 192 -> 16 nodes.
__global__ __launch_bounds__(192) void gather_k(
    const int* __restrict__ csr_src, const int* __restrict__ offsets,
    const float* __restrict__ dis, const unsigned short* __restrict__ hp,
    unsigned short* __restrict__ aggH, unsigned short* __restrict__ aggL, int n) {
  const int tid  = threadIdx.x;
  const int node = blockIdx.x * 16 + tid / 12;
  const int q    = tid % 12;
  if (node >= n) return;
  float a[8] = {0.f, 0.f, 0.f, 0.f, 0.f, 0.f, 0.f, 0.f};
  acc8(a, ((const uint4*)(hp + (size_t)node * HDIM))[q]);   // self term
  int i = offsets[node];
  const int end = offsets[node + 1];
  for (; i + 3 < end; i += 4) {
    const int s0 = csr_src[i], s1 = csr_src[i + 1], s2 = csr_src[i + 2], s3 = csr_src[i + 3];
    const uint4 p0 = ((const uint4*)(hp + (size_t)s0 * HDIM))[q];
    const uint4 p1 = ((const uint4*)(hp + (size_t)s1 * HDIM))[q];
    const uint4 p2 = ((const uint4*)(hp + (size_t)s2 * HDIM))[q];
    const uint4 p3 = ((const uint4*)(hp + (size_t)s3 * HDIM))[q];
    acc8(a, p0); acc8(a, p1); acc8(a, p2); acc8(a, p3);
  }
  for (; i < end; i++) {
    acc8(a, ((const uint4*)(hp + (size_t)csr_src[i] * HDIM))[q]);
  }
  const float dd = dis[node];
  ushort4 h0, l0, h1, l1;
  split2(a[0] * dd, h0.x, l0.x); split2(a[1] * dd, h0.y, l0.y);
  split2(a[2] * dd, h0.z, l0.z); split2(a[3] * dd, h0.w, l0.w);
  split2(a[4] * dd, h1.x, l1.x); split2(a[5] * dd, h1.y, l1.y);
  split2(a[6] * dd, h1.z, l1.z); split2(a[7] * dd, h1.w, l1.w);
  const size_t base = (size_t)node * HDIM + 8 * q;
  *(ushort4*)(aggH + base)     = h0;
  *(ushort4*)(aggH + base + 4) = h1;
  *(ushort4*)(aggL + base)     = l0;
  *(ushort4*)(aggL + base + 4) = l1;
}

// ---- split-bf16 MFMA GEMM, copy-only staging ----
// out[M,96] = [A0|A1][M, 96*nkt] @ W[96*nkt, 96] + bias via 3-term split
// (Ahi*Whi + Ahi*Wlo + Alo*Whi). A arrives pre-split (hi/lo ushort [M][96]);
// W arrives pre-split+transposed ([n][k] tiles of 9216). Staging = uint4 copies.
// Block 256 = 4 waves; tile 64 rows; wave wv -> rows [16wv,16wv+16) x 96.
// MODE 0: fp32 out (no relu). MODE 1: relu -> split hi/lo pair out.
// MODE 2: relu*dis -> single bf16 msg out.
template<int MODE>
__global__ __launch_bounds__(256) void gemm_mfma_k(
    const unsigned short* __restrict__ AH0, const unsigned short* __restrict__ AL0,
    const unsigned short* __restrict__ AH1, const unsigned short* __restrict__ AL1,
    const unsigned short* __restrict__ WH, const unsigned short* __restrict__ WL,
    const float* __restrict__ bias, const float* __restrict__ dis,
    void* __restrict__ out0v, void* __restrict__ out1v, int M, int nkt) {
  __shared__ __align__(16) unsigned short Ah[64 * LSTR], Al[64 * LSTR];
  __shared__ __align__(16) unsigned short Wh[96 * LSTR], Wl[96 * LSTR];
  const int t = threadIdx.x;
  const int lane = t & 63, wv = t >> 6;
  const int m = lane & 15, quad = lane >> 4;
  const int row0 = blockIdx.x * 64;

  f32x4 acc[6];
#pragma unroll
  for (int c = 0; c < 6; c++) acc[c] = (f32x4){0.f, 0.f, 0.f, 0.f};

  for (int kt = 0; kt < nkt; kt++) {
    const unsigned short* AH = kt ? AH1 : AH0;
    const unsigned short* AL = kt ? AL1 : AL0;
    if (kt) __syncthreads();
    // stage A hi/lo: 64 rows x 12 uint4 each — pure copies
    for (int u = t; u < 768; u += 256) {
      const int r = u / 12, kq = u % 12;
      uint4 vh = make_uint4(0, 0, 0, 0), vl = make_uint4(0, 0, 0, 0);
      if (row0 + r < M) {
        vh = ((const uint4*)(AH + (size_t)(row0 + r) * HDIM))[kq];
        vl = ((const uint4*)(AL + (size_t)(row0 + r) * HDIM))[kq];
      }
      *(uint4*)(&Ah[r * LSTR + 8 * kq]) = vh;
      *(uint4*)(&Al[r * LSTR + 8 * kq]) = vl;
    }
    // stage W hi/lo: 96 rows x 12 uint4 each — pure copies
    const unsigned short* WHt = WH + (size_t)kt * 9216;
    const unsigned short* WLt = WL + (size_t)kt * 9216;
    for (int u = t; u < 1152; u += 256) {
      const int nn = u / 12, kq = u % 12;
      *(uint4*)(&Wh[nn * LSTR + 8 * kq]) = ((const uint4*)(WHt + (size_t)nn * HDIM))[kq];
      *(uint4*)(&Wl[nn * LSTR + 8 * kq]) = ((const uint4*)(WLt + (size_t)nn * HDIM))[kq];
    }
    __syncthreads();
#pragma unroll
    for (int kc = 0; kc < 3; kc++) {
      const int ko = 32 * kc + 8 * quad;
      const bf16x8 ah = *(const bf16x8*)(&Ah[(16 * wv + m) * LSTR + ko]);
      const bf16x8 al = *(const bf16x8*)(&Al[(16 * wv + m) * LSTR + ko]);
#pragma unroll
      for (int c = 0; c < 6; c++) {
        const bf16x8 wh = *(const bf16x8*)(&Wh[(16 * c + m) * LSTR + ko]);
        const bf16x8 wl = *(const bf16x8*)(&Wl[(16 * c + m) * LSTR + ko]);
        acc[c] = __builtin_amdgcn_mfma_f32_16x16x32_bf16(ah, wh, acc[c], 0, 0, 0);
        acc[c] = __builtin_amdgcn_mfma_f32_16x16x32_bf16(ah, wl, acc[c], 0, 0, 0);
        acc[c] = __builtin_amdgcn_mfma_f32_16x16x32_bf16(al, wh, acc[c], 0, 0, 0);
      }
    }
  }

  // epilogue: D col=lane&15, row(within 16) = quad*4 + r
  const int rbase = row0 + 16 * wv + 4 * quad;
  float dv[4];
  if (MODE == 2) {
#pragma unroll
    for (int r = 0; r < 4; r++) dv[r] = (rbase + r < M) ? dis[rbase + r] : 0.f;
  }
#pragma unroll
  for (int c = 0; c < 6; c++) {
    const int col = 16 * c + m;
    const float bv = bias[col];
#pragma unroll
    for (int r = 0; r < 4; r++) {
      const int row = rbase + r;
      if (row < M) {
        float v = acc[c][r] + bv;
        if (MODE != 0) v = fmaxf(v, 0.f);
        const size_t idx = (size_t)row * HDIM + col;
        if (MODE == 0) {
          ((float*)out0v)[idx] = v;
        } else if (MODE == 1) {
          unsigned short h, l;
          split2(v, h, l);
          ((unsigned short*)out0v)[idx] = h;
          ((unsigned short*)out1v)[idx] = l;
        } else {
          ((unsigned short*)out0v)[idx] = bf16rne(v * dv[r]);
        }
      }
    }
  }
}

extern "C" void kernel_launch(void* const* d_in, const int* in_sizes, int n_in,
                              void* d_out, int out_size, void* d_ws, size_t ws_size,
                              hipStream_t stream) {
  const float* x       = (const float*)d_in[0];
  const int*   edge    = (const int*)d_in[1];
  const float* W_local = (const float*)d_in[2];
  const float* b_local = (const float*)d_in[3];
  const float* W_g1    = (const float*)d_in[4];
  const float* b_g1    = (const float*)d_in[5];
  const float* W_g2    = (const float*)d_in[6];
  const float* b_g2    = (const float*)d_in[7];
  const float* W_fuse  = (const float*)d_in[8]; // [192, 96] row-major
  const float* b_fuse  = (const float*)d_in[9];
  float* out = (float*)d_out;

  const int n = in_sizes[0] / HDIM;
  const int e = in_sizes[1] / 2;
  const int* src = edge;
  const int* dst = edge + e;
  const int nb = (n + 1023) / 1024;

  char* ws = (char*)d_ws;
  auto alloc = [&](size_t bytes) { char* p = ws; ws += (bytes + 255) & ~(size_t)255; return p; };
  int*   indeg   = (int*)alloc((size_t)n * 4);
  float* dis     = (float*)alloc((size_t)n * 4);
  int*   offsets = (int*)alloc((size_t)(n + 1) * 4);
  int*   bsum    = (int*)alloc((size_t)nb * 4);
  int*   bbase   = (int*)alloc((size_t)nb * 4);
  int*   rank    = (int*)alloc((size_t)e * 4);
  int*   csr_src = (int*)alloc((size_t)e * 4);
  const size_t mat16 = (size_t)n * HDIM * 2;   // bf16 node-feature matrix
  unsigned short* msg16 = (unsigned short*)alloc(mat16);  // x' then g1'
  unsigned short* aggH  = (unsigned short*)alloc(mat16);  // ax / ag2 hi
  unsigned short* aggL  = (unsigned short*)alloc(mat16);  //          lo
  unsigned short* locH  = (unsigned short*)alloc(mat16);  // local hi
  unsigned short* locL  = (unsigned short*)alloc(mat16);
  unsigned short* g2H   = (unsigned short*)alloc(mat16);  // g2 hi
  unsigned short* g2L   = (unsigned short*)alloc(mat16);
  unsigned short* wH    = (unsigned short*)alloc(5 * 9216 * 2);  // pre-split W tiles
  unsigned short* wL    = (unsigned short*)alloc(5 * 9216 * 2);

  zero_k<<<(n + 255) / 256, 256, 0, stream>>>(indeg, n);
  deg_rank_k<<<(e + 255) / 256, 256, 0, stream>>>(dst, indeg, rank, e);
  scan_a_k<<<nb, 1024, 0, stream>>>(indeg, bsum, n);
  scan_b_k<<<1, 1024, 0, stream>>>(bsum, bbase, offsets, nb, n);
  scan_c_k<<<nb, 1024, 0, stream>>>(indeg, bbase, offsets, dis, n);
  place_k<<<(e + 255) / 256, 256, 0, stream>>>(src, dst, rank, offsets, csr_src, e);
  split_w_k<<<(5 * 9216 + 255) / 256, 256, 0, stream>>>(W_local, W_g1, W_g2, W_fuse, wH, wL);

  const int ggrid = (n + 15) / 16;
  const int gb = (n + 63) / 64;

  // x' = bf16(dis·x)
  scale_bf16_k<<<(n * 24 + 255) / 256, 256, 0, stream>>>(x, dis, msg16, n);
  // ax = dis·(x'[d] + Σ x'[s])  -> split hi/lo
  gather_k<<<ggrid, 192, 0, stream>>>(csr_src, offsets, dis, msg16, aggH, aggL, n);
  // local = relu(ax@W_local+b) -> split;  g1' = bf16(dis·relu(ax@W_g1+b)) -> msg16
  gemm_mfma_k<1><<<gb, 256, 0, stream>>>(aggH, aggL, nullptr, nullptr, wH, wL,
                                         b_local, nullptr, locH, locL, n, 1);
  gemm_mfma_k<2><<<gb, 256, 0, stream>>>(aggH, aggL, nullptr, nullptr, wH + 9216, wL + 9216,
                                         b_g1, dis, msg16, nullptr, n, 1);
  // ag2 = dis·(g1'[d] + Σ g1'[s]) -> split;  g2 = relu(ag2@W_g2+b) -> split
  gather_k<<<ggrid, 192, 0, stream>>>(csr_src, offsets, dis, msg16, aggH, aggL, n);
  gemm_mfma_k<1><<<gb, 256, 0, stream>>>(aggH, aggL, nullptr, nullptr, wH + 2 * 9216, wL + 2 * 9216,
                                         b_g2, nullptr, g2H, g2L, n, 1);
  // out = [local | g2] @ W_fuse + b_fuse   (K=192: tiles 3,4)
  gemm_mfma_k<0><<<gb, 256, 0, stream>>>(locH, locL, g2H, g2L, wH + 3 * 9216, wL + 3 * 9216,
                                         b_fuse, nullptr, out, nullptr, n, 2);
}

// Round 13
// 285.551 us; speedup vs baseline: 1.2757x; 1.0567x over previous
//
#include <hip/hip_runtime.h>

#define HDIM 96
#define LSTR 104   // LDS row stride in bf16 elems (96 + 8 pad); 208 B (16B-aligned rows, 2-way-free reads)

typedef __attribute__((ext_vector_type(8))) short bf16x8;   // 8 bf16 = 4 VGPRs
typedef __attribute__((ext_vector_type(4))) float f32x4;

__device__ __forceinline__ unsigned short bf16rne(float x) {
  const unsigned u = __float_as_uint(x);
  return (unsigned short)((u + 0x7fff + ((u >> 16) & 1)) >> 16);
}

// fp32 -> (hi, lo) truncated bf16 pair; x ~= hi + lo with ~2^-16 rel error
__device__ __forceinline__ void split2(float x, unsigned short& hi, unsigned short& lo) {
  const unsigned u = __float_as_uint(x);
  hi = (unsigned short)(u >> 16);
  const float xhi = __uint_as_float(u & 0xffff0000u);
  lo = (unsigned short)(__float_as_uint(x - xhi) >> 16);
}

__global__ void zero_k(int* __restrict__ p, int n) {
  int i = blockIdx.x * blockDim.x + threadIdx.x;
  if (i < n) p[i] = 0;
}

__global__ void deg_rank_k(const int* __restrict__ dst, int* __restrict__ indeg,
                           int* __restrict__ rank, int e) {
  int i = blockIdx.x * blockDim.x + threadIdx.x;
  if (i < e) rank[i] = atomicAdd(&indeg[dst[i]], 1);
}

__device__ __forceinline__ int wave_incl_scan(int v, int lane) {
#pragma unroll
  for (int off = 1; off < 64; off <<= 1) {
    int t = __shfl_up(v, off, 64);
    if (lane >= off) v += t;
  }
  return v;
}

__global__ __launch_bounds__(1024) void scan_a_k(const int* __restrict__ indeg,
                                                 int* __restrict__ bsum, int n) {
  const int tid = threadIdx.x;
  const int i = blockIdx.x * 1024 + tid;
  int v = (i < n) ? indeg[i] : 0;
#pragma unroll
  for (int off = 32; off; off >>= 1) v += __shfl_down(v, off, 64);
  __shared__ int ws[16];
  if ((tid & 63) == 0) ws[tid >> 6] = v;
  __syncthreads();
  if (tid < 16) {
    int s = ws[tid];
#pragma unroll
    for (int off = 8; off; off >>= 1) s += __shfl_down(s, off, 16);
    if (tid == 0) bsum[blockIdx.x] = s;
  }
}

__global__ __launch_bounds__(1024) void scan_b_k(const int* __restrict__ bsum,
                                                 int* __restrict__ bbase,
                                                 int* __restrict__ offsets, int nb, int n) {
  __shared__ int ws[16];
  const int tid = threadIdx.x, lane = tid & 63, w = tid >> 6;
  const int v = (tid < nb) ? bsum[tid] : 0;
  int incl = wave_incl_scan(v, lane);
  if (lane == 63) ws[w] = incl;
  __syncthreads();
  if (tid < 16) {
    int s = ws[tid];
#pragma unroll
    for (int off = 1; off < 16; off <<= 1) {
      int t = __shfl_up(s, off, 16);
      if (tid >= off) s += t;
    }
    ws[tid] = s;
  }
  __syncthreads();
  incl += (w > 0 ? ws[w - 1] : 0);
  if (tid < nb) bbase[tid] = incl - v;
  if (tid == 0) offsets[n] = ws[15];
}

__global__ __launch_bounds__(1024) void scan_c_k(const int* __restrict__ indeg,
                                                 const int* __restrict__ bbase,
                                                 int* __restrict__ offsets,
                                                 float* __restrict__ dis, int n) {
  __shared__ int ws[16];
  const int tid = threadIdx.x, lane = tid & 63, w = tid >> 6;
  const int i = blockIdx.x * 1024 + tid;
  const int v = (i < n) ? indeg[i] : 0;
  int incl = wave_incl_scan(v, lane);
  if (lane == 63) ws[w] = incl;
  __syncthreads();
  if (tid < 16) {
    int s = ws[tid];
#pragma unroll
    for (int off = 1; off < 16; off <<= 1) {
      int t = __shfl_up(s, off, 16);
      if (tid >= off) s += t;
    }
    ws[tid] = s;
  }
  __syncthreads();
  incl += (w > 0 ? ws[w - 1] : 0);
  if (i < n) {
    offsets[i] = bbase[blockIdx.x] + incl - v;
    dis[i] = rsqrtf((float)(1 + v));
  }
}

__global__ void place_k(const int* __restrict__ src, const int* __restrict__ dst,
                        const int* __restrict__ rank, const int* __restrict__ offsets,
                        int* __restrict__ csr_src, int e) {
  int i = blockIdx.x * blockDim.x + threadIdx.x;
  if (i >= e) return;
  int d = dst[i];
  atomicExch(&csr_src[offsets[d] + rank[i]], src[i]);
}

// Pre-split ALL weights once into bf16 hi/lo, B-fragment-ready [n][k] layout.
// 5 tiles of 96x96: 0=W_local, 1=W_g1, 2=W_g2, 3=W_fuse[0:96], 4=W_fuse[96:192].
__global__ void split_w_k(const float* __restrict__ W0, const float* __restrict__ W1,
                          const float* __restrict__ W2, const float* __restrict__ W3,
                          unsigned short* __restrict__ dH, unsigned short* __restrict__ dL) {
  const int t = blockIdx.x * blockDim.x + threadIdx.x;
  if (t >= 5 * 9216) return;
  const int tile = t / 9216, r = t % 9216;
  const int nn = r / 96, k = r % 96;
  const float* W = (tile == 0) ? W0 : (tile == 1) ? W1 : (tile == 2) ? W2 : W3;
  const int row = (tile == 4) ? 96 + k : k;
  unsigned short h, l;
  split2(W[row * 96 + nn], h, l);
  dH[t] = h;
  dL[t] = l;
}

// o[i,:] = bf16( dis[i] * x[i,:] )
__global__ void scale_bf16_k(const float* __restrict__ x, const float* __restrict__ dis,
                             unsigned short* __restrict__ o, int n) {
  int t = blockIdx.x * blockDim.x + threadIdx.x;
  if (t >= n * 24) return;
  const float d = dis[t / 24];
  float4 v = ((const float4*)x)[t];
  ushort4 h;
  h.x = bf16rne(v.x * d); h.y = bf16rne(v.y * d);
  h.z = bf16rne(v.z * d); h.w = bf16rne(v.w * d);
  ((ushort4*)o)[t] = h;
}

__device__ __forceinline__ void acc8(float* a, uint4 p) {
  a[0] += __uint_as_float(p.x << 16);
  a[1] += __uint_as_float(p.x & 0xffff0000u);
  a[2] += __uint_as_float(p.y << 16);
  a[3] += __uint_as_float(p.y & 0xffff0000u);
  a[4] += __uint_as_float(p.z << 16);
  a[5] += __uint_as_float(p.z & 0xffff0000u);
  a[6] += __uint_as_float(p.w << 16);
  a[7] += __uint_as_float(p.w & 0xffff0000u);
}

// ---- fused gather + split-bf16 MFMA GEMM ----
// For 64 nodes/block: agg[d] = dis[d]*(hp[d] + sum hp[s]) gathered so that each
// thread's fp32 accumulator IS its MFMA A-fragment (node=row0+16wv+m, k-chunks
// at 32kc+8quad..+7). split2 -> ah/al frags in REGISTERS (no A LDS, no barrier
// between gather and MFMA). LDS holds only W hi/lo (39.9 KB -> 4 blocks/CU).
// Set0: out = relu(z)+split -> (outH,outL). DUAL set1 (W restaged): outMsg =
// bf16rne(dis*relu(z1)) — the pre-scaled message for the next hop.
template<bool DUAL>
__global__ __launch_bounds__(256) void gat_gemm_k(
    const int* __restrict__ csr_src, const int* __restrict__ offsets,
    const float* __restrict__ dis, const unsigned short* __restrict__ hp,
    const unsigned short* __restrict__ WH0, const unsigned short* __restrict__ WL0,
    const float* __restrict__ b0,
    const unsigned short* __restrict__ WH1, const unsigned short* __restrict__ WL1,
    const float* __restrict__ b1,
    unsigned short* __restrict__ outH, unsigned short* __restrict__ outL,
    unsigned short* __restrict__ outMsg, int M) {
  __shared__ __align__(16) unsigned short Wh[96 * LSTR], Wl[96 * LSTR];
  const int t = threadIdx.x;
  const int lane = t & 63, wv = t >> 6;
  const int m = lane & 15, quad = lane >> 4;
  const int row0 = blockIdx.x * 64;
  const int node = row0 + 16 * wv + m;

  // stage W set0 (pure uint4 copies)
  for (int u = t; u < 1152; u += 256) {
    const int nn = u / 12, kq = u % 12;
    *(uint4*)(&Wh[nn * LSTR + 8 * kq]) = ((const uint4*)(WH0 + (size_t)nn * HDIM))[kq];
    *(uint4*)(&Wl[nn * LSTR + 8 * kq]) = ((const uint4*)(WL0 + (size_t)nn * HDIM))[kq];
  }

  // gather: a[kc][j] accumulates k = 32*kc + 8*quad + j  (== A-frag layout)
  float a[3][8];
#pragma unroll
  for (int c = 0; c < 3; c++)
#pragma unroll
    for (int j = 0; j < 8; j++) a[c][j] = 0.f;
  if (node < M) {
    const unsigned short* selfp = hp + (size_t)node * HDIM + 8 * quad;
    acc8(a[0], *(const uint4*)(selfp));
    acc8(a[1], *(const uint4*)(selfp + 32));
    acc8(a[2], *(const uint4*)(selfp + 64));
    int i = offsets[node];
    const int end = offsets[node + 1];
    for (; i + 1 < end; i += 2) {
      const unsigned short* p0 = hp + (size_t)csr_src[i] * HDIM + 8 * quad;
      const unsigned short* p1 = hp + (size_t)csr_src[i + 1] * HDIM + 8 * quad;
      const uint4 v00 = *(const uint4*)(p0), v01 = *(const uint4*)(p0 + 32), v02 = *(const uint4*)(p0 + 64);
      const uint4 v10 = *(const uint4*)(p1), v11 = *(const uint4*)(p1 + 32), v12 = *(const uint4*)(p1 + 64);
      acc8(a[0], v00); acc8(a[1], v01); acc8(a[2], v02);
      acc8(a[0], v10); acc8(a[1], v11); acc8(a[2], v12);
    }
    if (i < end) {
      const unsigned short* p0 = hp + (size_t)csr_src[i] * HDIM + 8 * quad;
      acc8(a[0], *(const uint4*)(p0));
      acc8(a[1], *(const uint4*)(p0 + 32));
      acc8(a[2], *(const uint4*)(p0 + 64));
    }
    const float dd = dis[node];
#pragma unroll
    for (int c = 0; c < 3; c++)
#pragma unroll
      for (int j = 0; j < 8; j++) a[c][j] *= dd;
  }
  // split to A fragments in registers
  bf16x8 ah[3], al[3];
#pragma unroll
  for (int c = 0; c < 3; c++)
#pragma unroll
    for (int j = 0; j < 8; j++) {
      unsigned short h, l;
      split2(a[c][j], h, l);
      ah[c][j] = (short)h;
      al[c][j] = (short)l;
    }

  __syncthreads();   // W set0 visible

  f32x4 acc0[6];
#pragma unroll
  for (int c = 0; c < 6; c++) acc0[c] = (f32x4){0.f, 0.f, 0.f, 0.f};
#pragma unroll
  for (int kc = 0; kc < 3; kc++) {
    const int ko = 32 * kc + 8 * quad;
#pragma unroll
    for (int c = 0; c < 6; c++) {
      const bf16x8 wh = *(const bf16x8*)(&Wh[(16 * c + m) * LSTR + ko]);
      const bf16x8 wl = *(const bf16x8*)(&Wl[(16 * c + m) * LSTR + ko]);
      acc0[c] = __builtin_amdgcn_mfma_f32_16x16x32_bf16(ah[kc], wh, acc0[c], 0, 0, 0);
      acc0[c] = __builtin_amdgcn_mfma_f32_16x16x32_bf16(ah[kc], wl, acc0[c], 0, 0, 0);
      acc0[c] = __builtin_amdgcn_mfma_f32_16x16x32_bf16(al[kc], wh, acc0[c], 0, 0, 0);
    }
  }

  // epilogue set0: relu -> split pair.  D: col=16c+m, row = row0+16wv+4quad+r
  const int rbase = row0 + 16 * wv + 4 * quad;
#pragma unroll
  for (int c = 0; c < 6; c++) {
    const int col = 16 * c + m;
    const float bv = b0[col];
#pragma unroll
    for (int r = 0; r < 4; r++) {
      const int row = rbase + r;
      if (row < M) {
        const float v = fmaxf(acc0[c][r] + bv, 0.f);
        unsigned short h, l;
        split2(v, h, l);
        const size_t idx = (size_t)row * HDIM + col;
        outH[idx] = h;
        outL[idx] = l;
      }
    }
  }

  if (DUAL) {
    __syncthreads();   // all waves done reading W set0
    for (int u = t; u < 1152; u += 256) {
      const int nn = u / 12, kq = u % 12;
      *(uint4*)(&Wh[nn * LSTR + 8 * kq]) = ((const uint4*)(WH1 + (size_t)nn * HDIM))[kq];
      *(uint4*)(&Wl[nn * LSTR + 8 * kq]) = ((const uint4*)(WL1 + (size_t)nn * HDIM))[kq];
    }
    __syncthreads();
    f32x4 acc1[6];
#pragma unroll
    for (int c = 0; c < 6; c++) acc1[c] = (f32x4){0.f, 0.f, 0.f, 0.f};
#pragma unroll
    for (int kc = 0; kc < 3; kc++) {
      const int ko = 32 * kc + 8 * quad;
#pragma unroll
      for (int c = 0; c < 6; c++) {
        const bf16x8 wh = *(const bf16x8*)(&Wh[(16 * c + m) * LSTR + ko]);
        const bf16x8 wl = *(const bf16x8*)(&Wl[(16 * c + m) * LSTR + ko]);
        acc1[c] = __builtin_amdgcn_mfma_f32_16x16x32_bf16(ah[kc], wh, acc1[c], 0, 0, 0);
        acc1[c] = __builtin_amdgcn_mfma_f32_16x16x32_bf16(ah[kc], wl, acc1[c], 0, 0, 0);
        acc1[c] = __builtin_amdgcn_mfma_f32_16x16x32_bf16(al[kc], wh, acc1[c], 0, 0, 0);
      }
    }
    float dv[4];
#pragma unroll
    for (int r = 0; r < 4; r++) dv[r] = (rbase + r < M) ? dis[rbase + r] : 0.f;
#pragma unroll
    for (int c = 0; c < 6; c++) {
      const int col = 16 * c + m;
      const float bv = b1[col];
#pragma unroll
      for (int r = 0; r < 4; r++) {
        const int row = rbase + r;
        if (row < M)
          outMsg[(size_t)row * HDIM + col] = bf16rne(fmaxf(acc1[c][r] + bv, 0.f) * dv[r]);
      }
    }
  }
}

// ---- concat GEMM (copy-only staging, pre-split A and W) ----
// out[M,96] = [A0|A1][M,192] @ Wfuse + bias, fp32 out.
__global__ __launch_bounds__(256) void gemm_concat_k(
    const unsigned short* __restrict__ AH0, const unsigned short* __restrict__ AL0,
    const unsigned short* __restrict__ AH1, const unsigned short* __restrict__ AL1,
    const unsigned short* __restrict__ WH, const unsigned short* __restrict__ WL,
    const float* __restrict__ bias, float* __restrict__ out, int M) {
  __shared__ __align__(16) unsigned short Ah[64 * LSTR], Al[64 * LSTR];
  __shared__ __align__(16) unsigned short Wh[96 * LSTR], Wl[96 * LSTR];
  const int t = threadIdx.x;
  const int lane = t & 63, wv = t >> 6;
  const int m = lane & 15, quad = lane >> 4;
  const int row0 = blockIdx.x * 64;

  f32x4 acc[6];
#pragma unroll
  for (int c = 0; c < 6; c++) acc[c] = (f32x4){0.f, 0.f, 0.f, 0.f};

  for (int kt = 0; kt < 2; kt++) {
    const unsigned short* AH = kt ? AH1 : AH0;
    const unsigned short* AL = kt ? AL1 : AL0;
    if (kt) __syncthreads();
    for (int u = t; u < 768; u += 256) {
      const int r = u / 12, kq = u % 12;
      uint4 vh = make_uint4(0, 0, 0, 0), vl = make_uint4(0, 0, 0, 0);
      if (row0 + r < M) {
        vh = ((const uint4*)(AH + (size_t)(row0 + r) * HDIM))[kq];
        vl = ((const uint4*)(AL + (size_t)(row0 + r) * HDIM))[kq];
      }
      *(uint4*)(&Ah[r * LSTR + 8 * kq]) = vh;
      *(uint4*)(&Al[r * LSTR + 8 * kq]) = vl;
    }
    const unsigned short* WHt = WH + (size_t)kt * 9216;
    const unsigned short* WLt = WL + (size_t)kt * 9216;
    for (int u = t; u < 1152; u += 256) {
      const int nn = u / 12, kq = u % 12;
      *(uint4*)(&Wh[nn * LSTR + 8 * kq]) = ((const uint4*)(WHt + (size_t)nn * HDIM))[kq];
      *(uint4*)(&Wl[nn * LSTR + 8 * kq]) = ((const uint4*)(WLt + (size_t)nn * HDIM))[kq];
    }
    __syncthreads();
#pragma unroll
    for (int kc = 0; kc < 3; kc++) {
      const int ko = 32 * kc + 8 * quad;
      const bf16x8 ah = *(const bf16x8*)(&Ah[(16 * wv + m) * LSTR + ko]);
      const bf16x8 al = *(const bf16x8*)(&Al[(16 * wv + m) * LSTR + ko]);
#pragma unroll
      for (int c = 0; c < 6; c++) {
        const bf16x8 wh = *(const bf16x8*)(&Wh[(16 * c + m) * LSTR + ko]);
        const bf16x8 wl = *(const bf16x8*)(&Wl[(16 * c + m) * LSTR + ko]);
        acc[c] = __builtin_amdgcn_mfma_f32_16x16x32_bf16(ah, wh, acc[c], 0, 0, 0);
        acc[c] = __builtin_amdgcn_mfma_f32_16x16x32_bf16(ah, wl, acc[c], 0, 0, 0);
        acc[c] = __builtin_amdgcn_mfma_f32_16x16x32_bf16(al, wh, acc[c], 0, 0, 0);
      }
    }
  }

  const int rbase = row0 + 16 * wv + 4 * quad;
#pragma unroll
  for (int c = 0; c < 6; c++) {
    const int col = 16 * c + m;
    const float bv = bias[col];
#pragma unroll
    for (int r = 0; r < 4; r++) {
      const int row = rbase + r;
      if (row < M) out[(size_t)row * HDIM + col] = acc[c][r] + bv;
    }
  }
}

extern "C" void kernel_launch(void* const* d_in, const int* in_sizes, int n_in,
                              void* d_out, int out_size, void* d_ws, size_t ws_size,
                              hipStream_t stream) {
  const float* x       = (const float*)d_in[0];
  const int*   edge    = (const int*)d_in[1];
  const float* W_local = (const float*)d_in[2];
  const float* b_local = (const float*)d_in[3];
  const float* W_g1    = (const float*)d_in[4];
  const float* b_g1    = (const float*)d_in[5];
  const float* W_g2    = (const float*)d_in[6];
  const float* b_g2    = (const float*)d_in[7];
  const float* W_fuse  = (const float*)d_in[8]; // [192, 96] row-major
  const float* b_fuse  = (const float*)d_in[9];
  float* out = (float*)d_out;

  const int n = in_sizes[0] / HDIM;
  const int e = in_sizes[1] / 2;
  const int* src = edge;
  const int* dst = edge + e;
  const int nb = (n + 1023) / 1024;

  char* ws = (char*)d_ws;
  auto alloc = [&](size_t bytes) { char* p = ws; ws += (bytes + 255) & ~(size_t)255; return p; };
  int*   indeg   = (int*)alloc((size_t)n * 4);
  float* dis     = (float*)alloc((size_t)n * 4);
  int*   offsets = (int*)alloc((size_t)(n + 1) * 4);
  int*   bsum    = (int*)alloc((size_t)nb * 4);
  int*   bbase   = (int*)alloc((size_t)nb * 4);
  int*   rank    = (int*)alloc((size_t)e * 4);
  int*   csr_src = (int*)alloc((size_t)e * 4);
  const size_t mat16 = (size_t)n * HDIM * 2;
  unsigned short* msgX = (unsigned short*)alloc(mat16);   // x' messages
  unsigned short* msgG = (unsigned short*)alloc(mat16);   // g1' messages
  unsigned short* locH = (unsigned short*)alloc(mat16);   // local hi/lo
  unsigned short* locL = (unsigned short*)alloc(mat16);
  unsigned short* g2H  = (unsigned short*)alloc(mat16);   // g2 hi/lo
  unsigned short* g2L  = (unsigned short*)alloc(mat16);
  unsigned short* wH   = (unsigned short*)alloc(5 * 9216 * 2);
  unsigned short* wL   = (unsigned short*)alloc(5 * 9216 * 2);

  zero_k<<<(n + 255) / 256, 256, 0, stream>>>(indeg, n);
  deg_rank_k<<<(e + 255) / 256, 256, 0, stream>>>(dst, indeg, rank, e);
  scan_a_k<<<nb, 1024, 0, stream>>>(indeg, bsum, n);
  scan_b_k<<<1, 1024, 0, stream>>>(bsum, bbase, offsets, nb, n);
  scan_c_k<<<nb, 1024, 0, stream>>>(indeg, bbase, offsets, dis, n);
  place_k<<<(e + 255) / 256, 256, 0, stream>>>(src, dst, rank, offsets, csr_src, e);
  split_w_k<<<(5 * 9216 + 255) / 256, 256, 0, stream>>>(W_local, W_g1, W_g2, W_fuse, wH, wL);

  const int gb = (n + 63) / 64;

  // x' = bf16(dis·x)
  scale_bf16_k<<<(n * 24 + 255) / 256, 256, 0, stream>>>(x, dis, msgX, n);
  // hop 1 fused: gather(x') -> ax frags; local = split(relu(ax@Wl+b)); g1' = msg(dis·relu(ax@Wg1+b))
  gat_gemm_k<true><<<gb, 256, 0, stream>>>(csr_src, offsets, dis, msgX,
                                           wH, wL, b_local,
                                           wH + 9216, wL + 9216, b_g1,
                                           locH, locL, msgG, n);
  // hop 2 fused: gather(g1') -> ag2 frags; g2 = split(relu(ag2@Wg2+b))
  gat_gemm_k<false><<<gb, 256, 0, stream>>>(csr_src, offsets, dis, msgG,
                                            wH + 2 * 9216, wL + 2 * 9216, b_g2,
                                            nullptr, nullptr, nullptr,
                                            g2H, g2L, nullptr, n);
  // out = [local | g2] @ W_fuse + b_fuse
  gemm_concat_k<<<gb, 256, 0, stream>>>(locH, locL, g2H, g2L,
                                        wH + 3 * 9216, wL + 3 * 9216, b_fuse, out, n);
}